// Round 6
// baseline (572.690 us; speedup 1.0000x reference)
//
#include <hip/hip_runtime.h>

// NodeGNN: h = lrelu(lrelu(x@W1+b1)@W2+b2); 2x GCNConv(16->16) over E=6.4M edges
// + self loops with symmetric norm; out = sum(h@pw+pb, -1). Returns (out[N], h[N,16]).
//
// R10: persistent pipelined MLP with fused hw1. R7 profile showed mlp_mfma with
// ALL pipes idle (Mfma 6.8%, VALU 15%, HBM 10%, Occ 28%) -> latency-bound; fix is
// persistent blocks (1024 = 4/CU resident) + register prefetch of tile t+1's x
// under tile t's MFMAs (issue-early/write-late). hw1 (16x16 matmul * dinv -> bf16
// rows) fused into the epilogue via LDS transpose: kills the 25.6MB h round-trip
// and a launch. Gathers/CSR chain unchanged (R9: gathers at divergent-tx floor).

#define NEG 0.01f
#define SHIFT 9                 // 512 nodes per bucket
#define BNODES (1 << SHIFT)
#define BMAX 512                // max buckets (N <= 262144)
#define PCHUNK 8192             // edges per partition block
#define H1S 268                 // h1s row stride (ushorts): cf epilogue writes
#define CSRCAP 19200            // LDS-staged bucket sort capacity (mean 16.4K +22sigma)
#define MLPGRID 1024            // persistent MLP blocks (4/CU)

typedef __attribute__((ext_vector_type(8))) short short8;
typedef __attribute__((ext_vector_type(4))) float floatx4;
typedef __attribute__((ext_vector_type(2))) float floatx2;
typedef __attribute__((ext_vector_type(4))) unsigned short us4;
typedef __attribute__((ext_vector_type(8))) unsigned short us8;

__device__ __forceinline__ float lrelu(float v) { return v >= 0.0f ? v : NEG * v; }

__device__ __forceinline__ unsigned short f2bf(float f) {
    unsigned int u = __float_as_uint(f);
    u += 0x7fffu + ((u >> 16) & 1u);          // round-to-nearest-even
    return (unsigned short)(u >> 16);
}
__device__ __forceinline__ float bflo(unsigned int u) { return __uint_as_float(u << 16); }
__device__ __forceinline__ float bfhi(unsigned int u) { return __uint_as_float(u & 0xffff0000u); }

// ---------------------------------------------------------------------------
// K-prep: bf16-transposed weights. W1T[n][k] = bf16(W1[k][n]) (256x128),
// W2T[c][k] = bf16(W2[k][c]) (16x256).
// ---------------------------------------------------------------------------
__global__ void prep_kernel(const float* __restrict__ W1, const float* __restrict__ W2,
                            unsigned short* __restrict__ W1T, unsigned short* __restrict__ W2T)
{
    const int idx = blockIdx.x * 256 + threadIdx.x;
    const int stride = gridDim.x * 256;
    for (int i = idx; i < 256 * 128; i += stride) {
        int n = i >> 7, k = i & 127;
        W1T[i] = f2bf(W1[k * 256 + n]);
    }
    for (int i = idx; i < 16 * 256; i += stride) {
        int c = i >> 8, k = i & 255;
        W2T[i] = f2bf(W2[k * 16 + c]);
    }
}

// ---------------------------------------------------------------------------
// K1: persistent MFMA MLP + fused hw1. Block = 256 threads (4 waves), 64
// nodes/tile, grid-stride over tiles. Register-prefetch of next tile's x
// issued after fragment reads, written to LDS after the epilogue.
// Epilogue: h (=lrelu(acc2+b2)) -> hbuf (fp32, stride 17) -> 16x16 @ cw0,
// scaled by dinv, packed bf16 -> hws rows. 'h' never touches global.
// ---------------------------------------------------------------------------
__global__ __launch_bounds__(256, 4) void mlp_mfma(
    const float* __restrict__ x, const unsigned short* __restrict__ W1T,
    const float* __restrict__ b1, const unsigned short* __restrict__ W2T,
    const float* __restrict__ b2, const float* __restrict__ cw0,
    const float* __restrict__ dinv, unsigned short* __restrict__ hws, int N)
{
    __shared__ unsigned short lds[64 * H1S];   // 34.3 KB (xbf overlays h1s)
    __shared__ float hbuf[64 * 17];            // 4.3 KB
    __shared__ float Wl[256];                  // 1 KB (cw0)
    unsigned short (*xbf)[136] = (unsigned short (*)[136])lds;
    unsigned short (*h1s)[H1S] = (unsigned short (*)[H1S])lds;

    const int tid  = threadIdx.x;
    const int lane = tid & 63;
    const int lr   = lane & 15;
    const int quad = lane >> 4;
    const int wv   = tid >> 6;
    const int T    = N / 64;                   // tiles

    Wl[tid] = cw0[tid];

    float4 xreg[8];
    {
        const float4* xg = (const float4*)(x) + (size_t)blockIdx.x * 2048;
#pragma unroll
        for (int i = 0; i < 8; ++i) xreg[i] = xg[tid + 256 * i];
    }

    for (int t = blockIdx.x; t < T; t += MLPGRID) {
        const int n0 = t * 64;

        // stage prefetched x into LDS as bf16
#pragma unroll
        for (int i = 0; i < 8; ++i) {
            int f = tid + 256 * i;
            float4 v = xreg[i];
            int r = f >> 5, c = (f & 31) * 4;
            us4 p;
            p.x = f2bf(v.x); p.y = f2bf(v.y); p.z = f2bf(v.z); p.w = f2bf(v.w);
            *(us4*)&xbf[r][c] = p;
        }
        __syncthreads();                       // B1: xbf ready

        short8 af[4][4];
#pragma unroll
        for (int m = 0; m < 4; ++m)
#pragma unroll
            for (int kt = 0; kt < 4; ++kt)
                af[m][kt] = *(const short8*)&xbf[m * 16 + lr][kt * 32 + quad * 8];
        __syncthreads();                       // B2: xbf consumed; region free for h1s

        // issue next tile's x loads (latency hidden under the MFMAs)
        if (t + MLPGRID < T) {
            const float4* xg = (const float4*)(x) + (size_t)(t + MLPGRID) * 2048;
#pragma unroll
            for (int i = 0; i < 8; ++i) xreg[i] = xg[tid + 256 * i];
        }

        floatx4 acc[4][4];
#pragma unroll
        for (int n = 0; n < 4; ++n)
#pragma unroll
            for (int m = 0; m < 4; ++m)
                acc[n][m] = (floatx4){0.f, 0.f, 0.f, 0.f};

        const int nbase = wv * 64;
#pragma unroll
        for (int n = 0; n < 4; ++n) {
            const unsigned short* bp = &W1T[(size_t)(nbase + n * 16 + lr) * 128 + quad * 8];
            short8 bfr[4];
#pragma unroll
            for (int kt = 0; kt < 4; ++kt) bfr[kt] = *(const short8*)(bp + kt * 32);
#pragma unroll
            for (int kt = 0; kt < 4; ++kt)
#pragma unroll
                for (int m = 0; m < 4; ++m)
                    acc[n][m] = __builtin_amdgcn_mfma_f32_16x16x32_bf16(
                        af[m][kt], bfr[kt], acc[n][m], 0, 0, 0);
        }

#pragma unroll
        for (int n = 0; n < 4; ++n) {
            float bc = b1[nbase + n * 16 + lr];
#pragma unroll
            for (int m = 0; m < 4; ++m)
#pragma unroll
                for (int reg = 0; reg < 4; ++reg) {
                    float v = lrelu(acc[n][m][reg] + bc);
                    h1s[m * 16 + quad * 4 + reg][nbase + n * 16 + lr] = f2bf(v);
                }
        }
        __syncthreads();                       // B3: h1s ready

        floatx4 acc2 = (floatx4){0.f, 0.f, 0.f, 0.f};
#pragma unroll
        for (int kt = 0; kt < 8; ++kt) {
            short8 a2 = *(const short8*)&h1s[wv * 16 + lr][kt * 32 + quad * 8];
            short8 b2f = *(const short8*)&W2T[lr * 256 + kt * 32 + quad * 8];
            acc2 = __builtin_amdgcn_mfma_f32_16x16x32_bf16(a2, b2f, acc2, 0, 0, 0);
        }
        float bb = b2[lr];
#pragma unroll
        for (int reg = 0; reg < 4; ++reg)
            hbuf[(wv * 16 + quad * 4 + reg) * 17 + lr] = lrelu(acc2[reg] + bb);
        __syncthreads();                       // B4: hbuf ready; h1s reads done

        // fused hw1: node = tid>>2, features c4..c4+3
        {
            const int node = tid >> 2;
            const int c4   = (tid & 3) * 4;
            float o0 = 0.f, o1 = 0.f, o2 = 0.f, o3 = 0.f;
#pragma unroll
            for (int k = 0; k < 16; ++k) {
                float vk = hbuf[node * 17 + k];
                floatx4 wr = *(const floatx4*)&Wl[k * 16 + c4];
                o0 += vk * wr.x; o1 += vk * wr.y; o2 += vk * wr.z; o3 += vk * wr.w;
            }
            float ds = dinv[n0 + node];
            us4 p;
            p.x = f2bf(o0 * ds); p.y = f2bf(o1 * ds);
            p.z = f2bf(o2 * ds); p.w = f2bf(o3 * ds);
            *(us4*)&hws[(size_t)(n0 + node) * 16 + c4] = p;
        }
        // no barrier: next iter's xbf store is fenced by B1, and the regions it
        // overwrites (h1s) were last READ before B4.
    }
}

// ---------------------------------------------------------------------------
// K0: zero the global bucket counters
// ---------------------------------------------------------------------------
__global__ void zero_kernel(int* __restrict__ bcnt)
{
    bcnt[threadIdx.x] = 0;
}

// ---------------------------------------------------------------------------
// K2: per-bucket edge histogram (LDS-aggregated)
// ---------------------------------------------------------------------------
__global__ __launch_bounds__(256) void bucket_count(
    const int* __restrict__ eidx, int* __restrict__ bcnt, int E, int N, int B)
{
    __shared__ int hist[BMAX];
    const int t = threadIdx.x;
    for (int b = t; b < B; b += 256) hist[b] = 0;
    __syncthreads();

    const int stride = gridDim.x * 256;
    for (int e = blockIdx.x * 256 + t; e < E; e += stride) {
        int d = eidx[E + e];
        d = min(max(d, 0), N - 1);
        atomicAdd(&hist[d >> SHIFT], 1);
    }
    __syncthreads();
    for (int b = t; b < B; b += 256) {
        int c = hist[b];
        if (c) atomicAdd(&bcnt[b], c);
    }
}

// ---------------------------------------------------------------------------
// K3: single-block exclusive scan over bucket counts
// ---------------------------------------------------------------------------
__global__ __launch_bounds__(512) void scan_kernel(
    const int* __restrict__ bcnt, int* __restrict__ bbase, int* __restrict__ gcur, int B)
{
    __shared__ int s[BMAX];
    const int t = threadIdx.x;        // 512 threads
    int c = (t < B) ? bcnt[t] : 0;
    s[t] = c;
    __syncthreads();
#pragma unroll
    for (int off = 1; off < BMAX; off <<= 1) {
        int v = s[t];
        int u = (t >= off) ? s[t - off] : 0;
        __syncthreads();
        s[t] = v + u;
        __syncthreads();
    }
    if (t < B) {
        int excl = s[t] - c;
        bbase[t] = excl;
        gcur[t]  = excl;
    }
    if (t == 0) bbase[B] = s[BMAX - 1];
}

// ---------------------------------------------------------------------------
// K4: partition via block-level LDS counting sort + coalesced run flush.
// ---------------------------------------------------------------------------
__global__ __launch_bounds__(512) void partition_kernel(
    const int* __restrict__ eidx, int* __restrict__ gcur, int* __restrict__ pairs,
    int E, int N, int B)
{
    __shared__ int hist[BMAX];        // count -> cursor
    __shared__ int offx[BMAX + 1];    // exclusive local offsets (kept intact)
    __shared__ int basec[BMAX];       // global run base for this block
    __shared__ int sorted[PCHUNK];    // 32KB; doubles as scan scratch
    const int t  = threadIdx.x;
    const int e0 = blockIdx.x * PCHUNK;
    const int elim = min(PCHUNK, E - e0);

    hist[t] = 0;
    __syncthreads();
    for (int i = t; i < elim; i += 512) {
        int d = eidx[E + e0 + i];
        d = min(max(d, 0), N - 1);
        atomicAdd(&hist[d >> SHIFT], 1);
    }
    __syncthreads();

    int c = hist[t];
    sorted[t] = c;
    __syncthreads();
#pragma unroll
    for (int o = 1; o < BMAX; o <<= 1) {
        int v = sorted[t];
        int u = (t >= o) ? sorted[t - o] : 0;
        __syncthreads();
        sorted[t] = v + u;
        __syncthreads();
    }
    const int excl = sorted[t] - c;
    offx[t] = excl;
    if (t == 0) offx[BMAX] = elim;
    basec[t] = (t < B && c) ? atomicAdd(&gcur[t], c) : 0;
    hist[t] = excl;                   // becomes local cursor
    __syncthreads();

    for (int i = t; i < elim; i += 512) {
        int s = eidx[e0 + i];
        int d = eidx[E + e0 + i];
        s = min(max(s, 0), N - 1);
        d = min(max(d, 0), N - 1);
        int b = d >> SHIFT;
        int p = atomicAdd(&hist[b], 1);
        sorted[p] = (s << SHIFT) | (d & (BNODES - 1));
    }
    __syncthreads();

    for (int slot = t; slot < elim; slot += 512) {
        int v = sorted[slot];
        int l = 0, r = BMAX - 1;
#pragma unroll
        for (int it = 0; it < 9; ++it) {
            int m = (l + r + 1) >> 1;
            if (offx[m] <= slot) l = m; else r = m - 1;
        }
        pairs[basec[l] + (slot - offx[l])] = v;
    }
}

// ---------------------------------------------------------------------------
// K5: per-bucket counting sort -> csr (LDS-staged, coalesced flush),
// plus row_start/cnt/dinv.
// ---------------------------------------------------------------------------
__global__ __launch_bounds__(512) void build_csr(
    const int* __restrict__ pairs, const int* __restrict__ bbase,
    int* __restrict__ row_start, int* __restrict__ cnt_out, float* __restrict__ dinv,
    int* __restrict__ csr, int N)
{
    __shared__ int cnt[BNODES];
    __shared__ int off[BNODES];
    __shared__ int sorted[CSRCAP];               // 75 KB -> 2 blocks/CU
    const int b = blockIdx.x, t = threadIdx.x;   // 512 threads
    const int node0 = b << SHIFT;
    const int lo = bbase[b], hi = bbase[b + 1];
    const int m = hi - lo;
    const bool fits = (m <= CSRCAP);             // statistically always true

    cnt[t] = 0;
    __syncthreads();
    for (int e = lo + t; e < hi; e += 512)
        atomicAdd(&cnt[pairs[e] & (BNODES - 1)], 1);
    __syncthreads();

    int c = cnt[t];
    off[t] = c;
    __syncthreads();
#pragma unroll
    for (int o = 1; o < BNODES; o <<= 1) {
        int v = off[t];
        int u = (t >= o) ? off[t - o] : 0;
        __syncthreads();
        off[t] = v + u;
        __syncthreads();
    }
    const int excl = off[t] - c;
    const int node = node0 + t;
    if (node < N) {
        row_start[node] = lo + excl;
        cnt_out[node]   = c;
        dinv[node]      = rsqrtf((float)(c + 1));
    }
    cnt[t] = excl;                   // local (0-based) cursor
    __syncthreads();
    for (int e = lo + t; e < hi; e += 512) {
        int v = pairs[e];
        int p = atomicAdd(&cnt[v & (BNODES - 1)], 1);
        int s = v >> SHIFT;
        if (fits) sorted[p] = s;
        else      csr[lo + p] = s;   // fallback (never statistically)
    }
    __syncthreads();
    if (fits)
        for (int i = t; i < m; i += 512)
            csr[lo + i] = sorted[i]; // coalesced flush
}

// ---------------------------------------------------------------------------
// K7a: layer-1 gather fused with layer-2 hw. 8 lanes/node, lane cp owns
// features 2cp,2cp+1. After the gather (rows pre-scaled by dinv_src):
//   agg = a*dinv_d; v = lrelu(agg + cb0); o = v @ cw1;  row2 = bf16(o*dinv_d)
// 16x16 matmul as an 8-lane shuffle rotation with cw1 in LDS.
// ---------------------------------------------------------------------------
__global__ __launch_bounds__(256) void gather_hw(
    const unsigned short* __restrict__ hws, const float* __restrict__ dinv,
    const int* __restrict__ csr, const int* __restrict__ row_start,
    const int* __restrict__ cnt, const float* __restrict__ cb0,
    const float* __restrict__ cw1, unsigned int* __restrict__ rows2, int N)
{
    __shared__ float Wl[256];
    Wl[threadIdx.x] = cw1[threadIdx.x];
    __syncthreads();

    int t    = blockIdx.x * 256 + threadIdx.x;
    int node = t >> 3;
    int cp   = t & 7;
    if (node >= N) return;

    const unsigned int* rows = (const unsigned int*)hws;   // row i = 8 uints

    int   s0 = row_start[node];
    int   n  = cnt[node];
    float di = dinv[node];
    unsigned int self = rows[(size_t)node * 8 + cp];
    float a0 = bflo(self), a1 = bfhi(self);

    int j = 0;
    for (; j + 8 <= n; j += 8) {
        int s[8];
#pragma unroll
        for (int u = 0; u < 8; ++u) s[u] = __builtin_nontemporal_load(&csr[s0 + j + u]);
        unsigned int v[8];
#pragma unroll
        for (int u = 0; u < 8; ++u) v[u] = rows[(size_t)s[u] * 8 + cp];
#pragma unroll
        for (int u = 0; u < 8; ++u) { a0 += bflo(v[u]); a1 += bfhi(v[u]); }
    }
    for (; j < n; ++j) {
        int s = __builtin_nontemporal_load(&csr[s0 + j]);
        unsigned int v = rows[(size_t)s * 8 + cp];
        a0 += bflo(v); a1 += bfhi(v);
    }

    float v0 = lrelu(a0 * di + cb0[2 * cp]);
    float v1 = lrelu(a1 * di + cb0[2 * cp + 1]);

    float o0 = 0.0f, o1 = 0.0f;
#pragma unroll
    for (int r = 0; r < 8; ++r) {
        int src = (cp + r) & 7;
        float vk0 = __shfl(v0, src, 8);
        float vk1 = __shfl(v1, src, 8);
        floatx2 wa = *(const floatx2*)&Wl[(2 * src) * 16 + 2 * cp];
        floatx2 wb = *(const floatx2*)&Wl[(2 * src + 1) * 16 + 2 * cp];
        o0 += vk0 * wa.x + vk1 * wb.x;
        o1 += vk0 * wa.y + vk1 * wb.y;
    }
    unsigned int u = (unsigned int)f2bf(o0 * di) | ((unsigned int)f2bf(o1 * di) << 16);
    rows2[(size_t)node * 8 + cp] = u;
}

// ---------------------------------------------------------------------------
// K7b: layer-2 gather fused with the final head.
//   v = lrelu(a*dinv_d + cb1);  hout = v;  out = sum(v .* (pw0+pw1)) + pb0+pb1
// ---------------------------------------------------------------------------
__global__ __launch_bounds__(256) void gather_final(
    const unsigned short* __restrict__ hws, const float* __restrict__ dinv,
    const int* __restrict__ csr, const int* __restrict__ row_start,
    const int* __restrict__ cnt, const float* __restrict__ cb1,
    const float* __restrict__ pw, const float* __restrict__ pb,
    float* __restrict__ out, float* __restrict__ hout, int N)
{
    int t    = blockIdx.x * 256 + threadIdx.x;
    int node = t >> 3;
    int cp   = t & 7;
    if (node >= N) return;

    const unsigned int* rows = (const unsigned int*)hws;   // row i = 8 uints

    int   s0 = row_start[node];
    int   n  = cnt[node];
    float di = dinv[node];
    unsigned int self = rows[(size_t)node * 8 + cp];
    float a0 = bflo(self), a1 = bfhi(self);

    int j = 0;
    for (; j + 8 <= n; j += 8) {
        int s[8];
#pragma unroll
        for (int u = 0; u < 8; ++u) s[u] = __builtin_nontemporal_load(&csr[s0 + j + u]);
        unsigned int v[8];
#pragma unroll
        for (int u = 0; u < 8; ++u) v[u] = rows[(size_t)s[u] * 8 + cp];
#pragma unroll
        for (int u = 0; u < 8; ++u) { a0 += bflo(v[u]); a1 += bfhi(v[u]); }
    }
    for (; j < n; ++j) {
        int s = __builtin_nontemporal_load(&csr[s0 + j]);
        unsigned int v = rows[(size_t)s * 8 + cp];
        a0 += bflo(v); a1 += bfhi(v);
    }

    float v0 = lrelu(a0 * di + cb1[2 * cp]);
    float v1 = lrelu(a1 * di + cb1[2 * cp + 1]);

    float s = v0 * (pw[4 * cp] + pw[4 * cp + 1]) + v1 * (pw[4 * cp + 2] + pw[4 * cp + 3]);
    s += __shfl_xor(s, 1, 8);
    s += __shfl_xor(s, 2, 8);
    s += __shfl_xor(s, 4, 8);
    if (cp == 0) out[node] = s + pb[0] + pb[1];

    floatx2 hv; hv.x = v0; hv.y = v1;
    __builtin_nontemporal_store(hv, (floatx2*)&hout[(size_t)node * 16 + 2 * cp]);
}

// ---------------------------------------------------------------------------
extern "C" void kernel_launch(void* const* d_in, const int* in_sizes, int n_in,
                              void* d_out, int out_size, void* d_ws, size_t ws_size,
                              hipStream_t stream)
{
    const float* x   = (const float*)d_in[0];
    const float* W1  = (const float*)d_in[1];
    const float* b1  = (const float*)d_in[2];
    const float* W2  = (const float*)d_in[3];
    const float* b2  = (const float*)d_in[4];
    const float* cw0 = (const float*)d_in[5];
    const float* cb0 = (const float*)d_in[6];
    const float* cw1 = (const float*)d_in[7];
    const float* cb1 = (const float*)d_in[8];
    const float* pw  = (const float*)d_in[9];
    const float* pb  = (const float*)d_in[10];
    const int*   eidx = (const int*)d_in[11];

    const int N = in_sizes[0] / 128;
    const int E = in_sizes[11] / 2;
    const int B = (N + BNODES - 1) >> SHIFT;

    // workspace carve-out (~61 MB); X region serves pairs -> rows2
    char* w = (char*)d_ws;
    unsigned short* hws = (unsigned short*)w; w += (size_t)N * 16 * 2;  // bf16 rows (32B)
    float* dinv    = (float*)w; w += (size_t)N * 4;
    int*   cnt     = (int*)w;   w += (size_t)N * 4;
    int*   row_st  = (int*)w;   w += (size_t)N * 4;
    int*   csr     = (int*)w;   w += (size_t)E * 4;
    char*  X       = w;         w += (size_t)E * 4;
    int*   bcnt    = (int*)w;   w += BMAX * 4;
    int*   bbase   = (int*)w;   w += (BMAX + 4) * 4;   // +4 keeps 16B alignment below
    int*   gcur    = (int*)w;   w += BMAX * 4;
    unsigned short* W1T = (unsigned short*)w; w += 256 * 128 * 2;  // 16B-aligned
    unsigned short* W2T = (unsigned short*)w; w += 16 * 256 * 2;

    int*          pairs = (int*)X;           // live: partition -> build_csr
    unsigned int* rows2 = (unsigned int*)X;  // live: gather_hw -> gather_final (pairs dead)

    float* out  = (float*)d_out;
    float* hout = out + N;

    const int nb_g = (N * 8 + 255) / 256;
    const int nb_p = (E + PCHUNK - 1) / PCHUNK;

    // CSR chain first so dinv exists before the MLP folds it into the rows.
    zero_kernel<<<1, BMAX, 0, stream>>>(bcnt);
    bucket_count<<<1024, 256, 0, stream>>>(eidx, bcnt, E, N, B);
    scan_kernel<<<1, BMAX, 0, stream>>>(bcnt, bbase, gcur, B);
    partition_kernel<<<nb_p, 512, 0, stream>>>(eidx, gcur, pairs, E, N, B);
    build_csr<<<B, 512, 0, stream>>>(pairs, bbase, row_st, cnt, dinv, csr, N);

    prep_kernel<<<32, 256, 0, stream>>>(W1, W2, W1T, W2T);
    mlp_mfma<<<MLPGRID, 256, 0, stream>>>(x, W1T, b1, W2T, b2, cw0, dinv, hws, N); // pairs dead

    gather_hw<<<nb_g, 256, 0, stream>>>(hws, dinv, csr, row_st, cnt, cb0, cw1, rows2, N);
    gather_final<<<nb_g, 256, 0, stream>>>((const unsigned short*)rows2, dinv, csr, row_st, cnt,
                                           cb1, pw, pb, out, hout, N);
}

// Round 7
// 524.253 us; speedup vs baseline: 1.0924x; 1.0924x over previous
//
#include <hip/hip_runtime.h>

// NodeGNN: h = lrelu(lrelu(x@W1+b1)@W2+b2); 2x GCNConv(16->16) over E=6.4M edges
// + self loops with symmetric norm; out = sum(h@pw+pb, -1). Returns (out[N], h[N,16]).
//
// R11: (a) un-spill the MLP: R10's persistent xreg prefetch pushed VGPRs past the
// (256,4) budget -> 205MB of scratch writes. Back to the R8 tile structure (one
// block per 64 nodes) with the hw1 fusion kept (epilogue: h -> hbuf -> @cw0*dinv
// -> bf16 rows; no h round-trip). (b) gather lane-tx experiment: fitted model
// across R5-R8 says gather time = per-lane divergent tx x 1cyc/CU (coalescer does
// NOT merge 8 lanes sharing a 32B row). Switch to 2 lanes/node with 16B uint4 row
// loads: 51.2M -> 12.8M lane-tx/layer. Pre-committed read: ~35us => tx-model;
// ~70-80 => L3-path bound (next: half-split); ~84 => 16B decomposes to 4B tx.

#define NEG 0.01f
#define SHIFT 9                 // 512 nodes per bucket
#define BNODES (1 << SHIFT)
#define BMAX 512                // max buckets (N <= 262144)
#define PCHUNK 8192             // edges per partition block
#define H1S 268                 // h1s row stride (ushorts): cf epilogue writes
#define CSRCAP 19200            // LDS-staged bucket sort capacity (mean 16.4K +22sigma)

typedef __attribute__((ext_vector_type(8))) short short8;
typedef __attribute__((ext_vector_type(4))) float floatx4;
typedef __attribute__((ext_vector_type(2))) float floatx2;
typedef __attribute__((ext_vector_type(4))) unsigned short us4;
typedef __attribute__((ext_vector_type(8))) unsigned short us8;

__device__ __forceinline__ float lrelu(float v) { return v >= 0.0f ? v : NEG * v; }

__device__ __forceinline__ unsigned short f2bf(float f) {
    unsigned int u = __float_as_uint(f);
    u += 0x7fffu + ((u >> 16) & 1u);          // round-to-nearest-even
    return (unsigned short)(u >> 16);
}
__device__ __forceinline__ float bflo(unsigned int u) { return __uint_as_float(u << 16); }
__device__ __forceinline__ float bfhi(unsigned int u) { return __uint_as_float(u & 0xffff0000u); }

// ---------------------------------------------------------------------------
// K-prep: bf16-transposed weights. W1T[n][k] = bf16(W1[k][n]) (256x128),
// W2T[c][k] = bf16(W2[k][c]) (16x256).
// ---------------------------------------------------------------------------
__global__ void prep_kernel(const float* __restrict__ W1, const float* __restrict__ W2,
                            unsigned short* __restrict__ W1T, unsigned short* __restrict__ W2T)
{
    const int idx = blockIdx.x * 256 + threadIdx.x;
    const int stride = gridDim.x * 256;
    for (int i = idx; i < 256 * 128; i += stride) {
        int n = i >> 7, k = i & 127;
        W1T[i] = f2bf(W1[k * 256 + n]);
    }
    for (int i = idx; i < 16 * 256; i += stride) {
        int c = i >> 8, k = i & 255;
        W2T[i] = f2bf(W2[k * 16 + c]);
    }
}

// ---------------------------------------------------------------------------
// K1: MFMA MLP + fused hw1. Block = 256 threads (4 waves), 64 nodes/block.
// LDS: xbf overlays h1s (34.3KB) + hbuf (4.3KB) + Wl (1KB) = 39.7KB, 4/CU.
// Epilogue: h=lrelu(acc2+b2) -> hbuf(fp32,stride17) -> @cw0, *dinv, bf16 rows.
// ---------------------------------------------------------------------------
__global__ __launch_bounds__(256, 4) void mlp_mfma(
    const float* __restrict__ x, const unsigned short* __restrict__ W1T,
    const float* __restrict__ b1, const unsigned short* __restrict__ W2T,
    const float* __restrict__ b2, const float* __restrict__ cw0,
    const float* __restrict__ dinv, unsigned short* __restrict__ hws, int N)
{
    __shared__ unsigned short lds[64 * H1S];   // 34.3 KB (xbf overlays h1s)
    __shared__ float hbuf[64 * 17];            // 4.3 KB
    __shared__ float Wl[256];                  // 1 KB (cw0)
    unsigned short (*xbf)[136] = (unsigned short (*)[136])lds;
    unsigned short (*h1s)[H1S] = (unsigned short (*)[H1S])lds;

    const int tid  = threadIdx.x;
    const int n0   = blockIdx.x * 64;
    const int lane = tid & 63;
    const int lr   = lane & 15;
    const int quad = lane >> 4;
    const int wv   = tid >> 6;

    Wl[tid] = cw0[tid];
    {
        const float4* xg = (const float4*)(x + (size_t)n0 * 128);
#pragma unroll
        for (int i = 0; i < 8; ++i) {
            int f = tid + 256 * i;
            float4 v = xg[f];
            int r = f >> 5, c = (f & 31) * 4;
            us4 p;
            p.x = f2bf(v.x); p.y = f2bf(v.y); p.z = f2bf(v.z); p.w = f2bf(v.w);
            *(us4*)&xbf[r][c] = p;
        }
    }
    __syncthreads();                       // B1: xbf ready

    short8 af[4][4];
#pragma unroll
    for (int m = 0; m < 4; ++m)
#pragma unroll
        for (int kt = 0; kt < 4; ++kt)
            af[m][kt] = *(const short8*)&xbf[m * 16 + lr][kt * 32 + quad * 8];
    __syncthreads();                       // B2: xbf consumed; region free for h1s

    floatx4 acc[4][4];
#pragma unroll
    for (int n = 0; n < 4; ++n)
#pragma unroll
        for (int m = 0; m < 4; ++m)
            acc[n][m] = (floatx4){0.f, 0.f, 0.f, 0.f};

    const int nbase = wv * 64;
#pragma unroll
    for (int n = 0; n < 4; ++n) {
        const unsigned short* bp = &W1T[(size_t)(nbase + n * 16 + lr) * 128 + quad * 8];
        short8 bfr[4];
#pragma unroll
        for (int kt = 0; kt < 4; ++kt) bfr[kt] = *(const short8*)(bp + kt * 32);
#pragma unroll
        for (int kt = 0; kt < 4; ++kt)
#pragma unroll
            for (int m = 0; m < 4; ++m)
                acc[n][m] = __builtin_amdgcn_mfma_f32_16x16x32_bf16(
                    af[m][kt], bfr[kt], acc[n][m], 0, 0, 0);
    }

#pragma unroll
    for (int n = 0; n < 4; ++n) {
        float bc = b1[nbase + n * 16 + lr];
#pragma unroll
        for (int m = 0; m < 4; ++m)
#pragma unroll
            for (int reg = 0; reg < 4; ++reg) {
                float v = lrelu(acc[n][m][reg] + bc);
                h1s[m * 16 + quad * 4 + reg][nbase + n * 16 + lr] = f2bf(v);
            }
    }
    __syncthreads();                       // B3: h1s ready

    floatx4 acc2 = (floatx4){0.f, 0.f, 0.f, 0.f};
#pragma unroll
    for (int kt = 0; kt < 8; ++kt) {
        short8 a2 = *(const short8*)&h1s[wv * 16 + lr][kt * 32 + quad * 8];
        short8 b2f = *(const short8*)&W2T[lr * 256 + kt * 32 + quad * 8];
        acc2 = __builtin_amdgcn_mfma_f32_16x16x32_bf16(a2, b2f, acc2, 0, 0, 0);
    }
    float bb = b2[lr];
#pragma unroll
    for (int reg = 0; reg < 4; ++reg)
        hbuf[(wv * 16 + quad * 4 + reg) * 17 + lr] = lrelu(acc2[reg] + bb);
    __syncthreads();                       // B4: hbuf ready

    // fused hw1: node = tid>>2, features c4..c4+3
    {
        const int node = tid >> 2;
        const int c4   = (tid & 3) * 4;
        float o0 = 0.f, o1 = 0.f, o2 = 0.f, o3 = 0.f;
#pragma unroll
        for (int k = 0; k < 16; ++k) {
            float vk = hbuf[node * 17 + k];
            floatx4 wr = *(const floatx4*)&Wl[k * 16 + c4];
            o0 += vk * wr.x; o1 += vk * wr.y; o2 += vk * wr.z; o3 += vk * wr.w;
        }
        float ds = dinv[n0 + node];
        us4 p;
        p.x = f2bf(o0 * ds); p.y = f2bf(o1 * ds);
        p.z = f2bf(o2 * ds); p.w = f2bf(o3 * ds);
        *(us4*)&hws[(size_t)(n0 + node) * 16 + c4] = p;
    }
}

// ---------------------------------------------------------------------------
// K0: zero the global bucket counters
// ---------------------------------------------------------------------------
__global__ void zero_kernel(int* __restrict__ bcnt)
{
    bcnt[threadIdx.x] = 0;
}

// ---------------------------------------------------------------------------
// K2: per-bucket edge histogram (LDS-aggregated)
// ---------------------------------------------------------------------------
__global__ __launch_bounds__(256) void bucket_count(
    const int* __restrict__ eidx, int* __restrict__ bcnt, int E, int N, int B)
{
    __shared__ int hist[BMAX];
    const int t = threadIdx.x;
    for (int b = t; b < B; b += 256) hist[b] = 0;
    __syncthreads();

    const int stride = gridDim.x * 256;
    for (int e = blockIdx.x * 256 + t; e < E; e += stride) {
        int d = eidx[E + e];
        d = min(max(d, 0), N - 1);
        atomicAdd(&hist[d >> SHIFT], 1);
    }
    __syncthreads();
    for (int b = t; b < B; b += 256) {
        int c = hist[b];
        if (c) atomicAdd(&bcnt[b], c);
    }
}

// ---------------------------------------------------------------------------
// K3: single-block exclusive scan over bucket counts
// ---------------------------------------------------------------------------
__global__ __launch_bounds__(512) void scan_kernel(
    const int* __restrict__ bcnt, int* __restrict__ bbase, int* __restrict__ gcur, int B)
{
    __shared__ int s[BMAX];
    const int t = threadIdx.x;        // 512 threads
    int c = (t < B) ? bcnt[t] : 0;
    s[t] = c;
    __syncthreads();
#pragma unroll
    for (int off = 1; off < BMAX; off <<= 1) {
        int v = s[t];
        int u = (t >= off) ? s[t - off] : 0;
        __syncthreads();
        s[t] = v + u;
        __syncthreads();
    }
    if (t < B) {
        int excl = s[t] - c;
        bbase[t] = excl;
        gcur[t]  = excl;
    }
    if (t == 0) bbase[B] = s[BMAX - 1];
}

// ---------------------------------------------------------------------------
// K4: partition via block-level LDS counting sort + coalesced run flush.
// ---------------------------------------------------------------------------
__global__ __launch_bounds__(512) void partition_kernel(
    const int* __restrict__ eidx, int* __restrict__ gcur, int* __restrict__ pairs,
    int E, int N, int B)
{
    __shared__ int hist[BMAX];        // count -> cursor
    __shared__ int offx[BMAX + 1];    // exclusive local offsets (kept intact)
    __shared__ int basec[BMAX];       // global run base for this block
    __shared__ int sorted[PCHUNK];    // 32KB; doubles as scan scratch
    const int t  = threadIdx.x;
    const int e0 = blockIdx.x * PCHUNK;
    const int elim = min(PCHUNK, E - e0);

    hist[t] = 0;
    __syncthreads();
    for (int i = t; i < elim; i += 512) {
        int d = eidx[E + e0 + i];
        d = min(max(d, 0), N - 1);
        atomicAdd(&hist[d >> SHIFT], 1);
    }
    __syncthreads();

    int c = hist[t];
    sorted[t] = c;
    __syncthreads();
#pragma unroll
    for (int o = 1; o < BMAX; o <<= 1) {
        int v = sorted[t];
        int u = (t >= o) ? sorted[t - o] : 0;
        __syncthreads();
        sorted[t] = v + u;
        __syncthreads();
    }
    const int excl = sorted[t] - c;
    offx[t] = excl;
    if (t == 0) offx[BMAX] = elim;
    basec[t] = (t < B && c) ? atomicAdd(&gcur[t], c) : 0;
    hist[t] = excl;                   // becomes local cursor
    __syncthreads();

    for (int i = t; i < elim; i += 512) {
        int s = eidx[e0 + i];
        int d = eidx[E + e0 + i];
        s = min(max(s, 0), N - 1);
        d = min(max(d, 0), N - 1);
        int b = d >> SHIFT;
        int p = atomicAdd(&hist[b], 1);
        sorted[p] = (s << SHIFT) | (d & (BNODES - 1));
    }
    __syncthreads();

    for (int slot = t; slot < elim; slot += 512) {
        int v = sorted[slot];
        int l = 0, r = BMAX - 1;
#pragma unroll
        for (int it = 0; it < 9; ++it) {
            int m = (l + r + 1) >> 1;
            if (offx[m] <= slot) l = m; else r = m - 1;
        }
        pairs[basec[l] + (slot - offx[l])] = v;
    }
}

// ---------------------------------------------------------------------------
// K5: per-bucket counting sort -> csr (LDS-staged, coalesced flush),
// plus row_start/cnt/dinv.
// ---------------------------------------------------------------------------
__global__ __launch_bounds__(512) void build_csr(
    const int* __restrict__ pairs, const int* __restrict__ bbase,
    int* __restrict__ row_start, int* __restrict__ cnt_out, float* __restrict__ dinv,
    int* __restrict__ csr, int N)
{
    __shared__ int cnt[BNODES];
    __shared__ int off[BNODES];
    __shared__ int sorted[CSRCAP];               // 75 KB -> 2 blocks/CU
    const int b = blockIdx.x, t = threadIdx.x;   // 512 threads
    const int node0 = b << SHIFT;
    const int lo = bbase[b], hi = bbase[b + 1];
    const int m = hi - lo;
    const bool fits = (m <= CSRCAP);             // statistically always true

    cnt[t] = 0;
    __syncthreads();
    for (int e = lo + t; e < hi; e += 512)
        atomicAdd(&cnt[pairs[e] & (BNODES - 1)], 1);
    __syncthreads();

    int c = cnt[t];
    off[t] = c;
    __syncthreads();
#pragma unroll
    for (int o = 1; o < BNODES; o <<= 1) {
        int v = off[t];
        int u = (t >= o) ? off[t - o] : 0;
        __syncthreads();
        off[t] = v + u;
        __syncthreads();
    }
    const int excl = off[t] - c;
    const int node = node0 + t;
    if (node < N) {
        row_start[node] = lo + excl;
        cnt_out[node]   = c;
        dinv[node]      = rsqrtf((float)(c + 1));
    }
    cnt[t] = excl;                   // local (0-based) cursor
    __syncthreads();
    for (int e = lo + t; e < hi; e += 512) {
        int v = pairs[e];
        int p = atomicAdd(&cnt[v & (BNODES - 1)], 1);
        int s = v >> SHIFT;
        if (fits) sorted[p] = s;
        else      csr[lo + p] = s;   // fallback (never statistically)
    }
    __syncthreads();
    if (fits)
        for (int i = t; i < m; i += 512)
            csr[lo + i] = sorted[i]; // coalesced flush
}

// ---------------------------------------------------------------------------
// K7a: layer-1 gather fused with layer-2 hw. 2 lanes/node, lane cp owns
// features 8cp..8cp+7, loaded as ONE uint4 (16B) per edge -> 2 lane-tx/edge.
//   agg = a*dinv_d; v = lrelu(agg + cb0); o = v @ cw1;  row2 = bf16(o*dinv_d)
// 16x16 matmul via width-2 shuffles with cw1 in LDS.
// ---------------------------------------------------------------------------
__global__ __launch_bounds__(256) void gather_hw(
    const unsigned short* __restrict__ hws, const float* __restrict__ dinv,
    const int* __restrict__ csr, const int* __restrict__ row_start,
    const int* __restrict__ cnt, const float* __restrict__ cb0,
    const float* __restrict__ cw1, uint4* __restrict__ rows2, int N)
{
    __shared__ float Wl[256];
    Wl[threadIdx.x] = cw1[threadIdx.x];
    __syncthreads();

    int t    = blockIdx.x * 256 + threadIdx.x;
    int node = t >> 1;
    int cp   = t & 1;
    if (node >= N) return;

    const uint4* rows = (const uint4*)hws;   // row i = 2 uint4

    int   s0 = row_start[node];
    int   n  = cnt[node];
    float di = dinv[node];

    uint4 self = rows[(size_t)node * 2 + cp];
    float a[8];
    a[0] = bflo(self.x); a[1] = bfhi(self.x);
    a[2] = bflo(self.y); a[3] = bfhi(self.y);
    a[4] = bflo(self.z); a[5] = bfhi(self.z);
    a[6] = bflo(self.w); a[7] = bfhi(self.w);

    int j = 0;
    for (; j + 4 <= n; j += 4) {
        int s[4];
#pragma unroll
        for (int u = 0; u < 4; ++u) s[u] = __builtin_nontemporal_load(&csr[s0 + j + u]);
        uint4 v[4];
#pragma unroll
        for (int u = 0; u < 4; ++u) v[u] = rows[(size_t)s[u] * 2 + cp];
#pragma unroll
        for (int u = 0; u < 4; ++u) {
            a[0] += bflo(v[u].x); a[1] += bfhi(v[u].x);
            a[2] += bflo(v[u].y); a[3] += bfhi(v[u].y);
            a[4] += bflo(v[u].z); a[5] += bfhi(v[u].z);
            a[6] += bflo(v[u].w); a[7] += bfhi(v[u].w);
        }
    }
    for (; j < n; ++j) {
        int s = __builtin_nontemporal_load(&csr[s0 + j]);
        uint4 v = rows[(size_t)s * 2 + cp];
        a[0] += bflo(v.x); a[1] += bfhi(v.x);
        a[2] += bflo(v.y); a[3] += bfhi(v.y);
        a[4] += bflo(v.z); a[5] += bfhi(v.z);
        a[6] += bflo(v.w); a[7] += bfhi(v.w);
    }

    float v0[8];
#pragma unroll
    for (int f = 0; f < 8; ++f) v0[f] = lrelu(a[f] * di + cb0[8 * cp + f]);

    float o[8];
#pragma unroll
    for (int c = 0; c < 8; ++c) o[c] = 0.0f;
#pragma unroll
    for (int k = 0; k < 8; ++k) {
        float vkl = __shfl(v0[k], 0, 2);     // feature k (from cp=0 lane)
        float vkh = __shfl(v0[k], 1, 2);     // feature 8+k (from cp=1 lane)
        floatx4 wa0 = *(const floatx4*)&Wl[k * 16 + 8 * cp];
        floatx4 wa1 = *(const floatx4*)&Wl[k * 16 + 8 * cp + 4];
        floatx4 wb0 = *(const floatx4*)&Wl[(8 + k) * 16 + 8 * cp];
        floatx4 wb1 = *(const floatx4*)&Wl[(8 + k) * 16 + 8 * cp + 4];
        o[0] += vkl * wa0.x + vkh * wb0.x;
        o[1] += vkl * wa0.y + vkh * wb0.y;
        o[2] += vkl * wa0.z + vkh * wb0.z;
        o[3] += vkl * wa0.w + vkh * wb0.w;
        o[4] += vkl * wa1.x + vkh * wb1.x;
        o[5] += vkl * wa1.y + vkh * wb1.y;
        o[6] += vkl * wa1.z + vkh * wb1.z;
        o[7] += vkl * wa1.w + vkh * wb1.w;
    }
    uint4 u;
    u.x = (unsigned int)f2bf(o[0] * di) | ((unsigned int)f2bf(o[1] * di) << 16);
    u.y = (unsigned int)f2bf(o[2] * di) | ((unsigned int)f2bf(o[3] * di) << 16);
    u.z = (unsigned int)f2bf(o[4] * di) | ((unsigned int)f2bf(o[5] * di) << 16);
    u.w = (unsigned int)f2bf(o[6] * di) | ((unsigned int)f2bf(o[7] * di) << 16);
    rows2[(size_t)node * 2 + cp] = u;
}

// ---------------------------------------------------------------------------
// K7b: layer-2 gather fused with the final head. 2 lanes/node, 16B row loads.
//   v = lrelu(a*dinv_d + cb1);  hout = v;  out = sum(v .* (pw0+pw1)) + pb0+pb1
// ---------------------------------------------------------------------------
__global__ __launch_bounds__(256) void gather_final(
    const unsigned short* __restrict__ hws, const float* __restrict__ dinv,
    const int* __restrict__ csr, const int* __restrict__ row_start,
    const int* __restrict__ cnt, const float* __restrict__ cb1,
    const float* __restrict__ pw, const float* __restrict__ pb,
    float* __restrict__ out, float* __restrict__ hout, int N)
{
    int t    = blockIdx.x * 256 + threadIdx.x;
    int node = t >> 1;
    int cp   = t & 1;
    if (node >= N) return;

    const uint4* rows = (const uint4*)hws;   // row i = 2 uint4

    int   s0 = row_start[node];
    int   n  = cnt[node];
    float di = dinv[node];

    uint4 self = rows[(size_t)node * 2 + cp];
    float a[8];
    a[0] = bflo(self.x); a[1] = bfhi(self.x);
    a[2] = bflo(self.y); a[3] = bfhi(self.y);
    a[4] = bflo(self.z); a[5] = bfhi(self.z);
    a[6] = bflo(self.w); a[7] = bfhi(self.w);

    int j = 0;
    for (; j + 4 <= n; j += 4) {
        int s[4];
#pragma unroll
        for (int u = 0; u < 4; ++u) s[u] = __builtin_nontemporal_load(&csr[s0 + j + u]);
        uint4 v[4];
#pragma unroll
        for (int u = 0; u < 4; ++u) v[u] = rows[(size_t)s[u] * 2 + cp];
#pragma unroll
        for (int u = 0; u < 4; ++u) {
            a[0] += bflo(v[u].x); a[1] += bfhi(v[u].x);
            a[2] += bflo(v[u].y); a[3] += bfhi(v[u].y);
            a[4] += bflo(v[u].z); a[5] += bfhi(v[u].z);
            a[6] += bflo(v[u].w); a[7] += bfhi(v[u].w);
        }
    }
    for (; j < n; ++j) {
        int s = __builtin_nontemporal_load(&csr[s0 + j]);
        uint4 v = rows[(size_t)s * 2 + cp];
        a[0] += bflo(v.x); a[1] += bfhi(v.x);
        a[2] += bflo(v.y); a[3] += bfhi(v.y);
        a[4] += bflo(v.z); a[5] += bfhi(v.z);
        a[6] += bflo(v.w); a[7] += bfhi(v.w);
    }

    float v0[8];
    float s = 0.0f;
#pragma unroll
    for (int f = 0; f < 8; ++f) {
        v0[f] = lrelu(a[f] * di + cb1[8 * cp + f]);
        int g = 8 * cp + f;
        s += v0[f] * (pw[2 * g] + pw[2 * g + 1]);
    }
    s += __shfl_xor(s, 1, 2);
    if (cp == 0) out[node] = s + pb[0] + pb[1];

    floatx4 h0, h1;
    h0.x = v0[0]; h0.y = v0[1]; h0.z = v0[2]; h0.w = v0[3];
    h1.x = v0[4]; h1.y = v0[5]; h1.z = v0[6]; h1.w = v0[7];
    float* hp = &hout[(size_t)node * 16 + 8 * cp];
    __builtin_nontemporal_store(h0, (floatx4*)hp);
    __builtin_nontemporal_store(h1, (floatx4*)(hp + 4));
}

// ---------------------------------------------------------------------------
extern "C" void kernel_launch(void* const* d_in, const int* in_sizes, int n_in,
                              void* d_out, int out_size, void* d_ws, size_t ws_size,
                              hipStream_t stream)
{
    const float* x   = (const float*)d_in[0];
    const float* W1  = (const float*)d_in[1];
    const float* b1  = (const float*)d_in[2];
    const float* W2  = (const float*)d_in[3];
    const float* b2  = (const float*)d_in[4];
    const float* cw0 = (const float*)d_in[5];
    const float* cb0 = (const float*)d_in[6];
    const float* cw1 = (const float*)d_in[7];
    const float* cb1 = (const float*)d_in[8];
    const float* pw  = (const float*)d_in[9];
    const float* pb  = (const float*)d_in[10];
    const int*   eidx = (const int*)d_in[11];

    const int N = in_sizes[0] / 128;
    const int E = in_sizes[11] / 2;
    const int B = (N + BNODES - 1) >> SHIFT;

    // workspace carve-out (~61 MB); X region serves pairs -> rows2
    char* w = (char*)d_ws;
    unsigned short* hws = (unsigned short*)w; w += (size_t)N * 16 * 2;  // bf16 rows (32B)
    float* dinv    = (float*)w; w += (size_t)N * 4;
    int*   cnt     = (int*)w;   w += (size_t)N * 4;
    int*   row_st  = (int*)w;   w += (size_t)N * 4;
    int*   csr     = (int*)w;   w += (size_t)E * 4;
    char*  X       = w;         w += (size_t)E * 4;
    int*   bcnt    = (int*)w;   w += BMAX * 4;
    int*   bbase   = (int*)w;   w += (BMAX + 4) * 4;   // +4 keeps 16B alignment below
    int*   gcur    = (int*)w;   w += BMAX * 4;
    unsigned short* W1T = (unsigned short*)w; w += 256 * 128 * 2;  // 16B-aligned
    unsigned short* W2T = (unsigned short*)w; w += 16 * 256 * 2;

    int*   pairs = (int*)X;             // live: partition -> build_csr
    uint4* rows2 = (uint4*)X;           // live: gather_hw -> gather_final (pairs dead)

    float* out  = (float*)d_out;
    float* hout = out + N;

    const int nb_g = (N * 2 + 255) / 256;
    const int nb_p = (E + PCHUNK - 1) / PCHUNK;

    // CSR chain first so dinv exists before the MLP folds it into the rows.
    zero_kernel<<<1, BMAX, 0, stream>>>(bcnt);
    bucket_count<<<1024, 256, 0, stream>>>(eidx, bcnt, E, N, B);
    scan_kernel<<<1, BMAX, 0, stream>>>(bcnt, bbase, gcur, B);
    partition_kernel<<<nb_p, 512, 0, stream>>>(eidx, gcur, pairs, E, N, B);
    build_csr<<<B, 512, 0, stream>>>(pairs, bbase, row_st, cnt, dinv, csr, N);

    prep_kernel<<<32, 256, 0, stream>>>(W1, W2, W1T, W2T);
    mlp_mfma<<<N / 64, 256, 0, stream>>>(x, W1T, b1, W2T, b2, cw0, dinv, hws, N); // pairs dead

    gather_hw<<<nb_g, 256, 0, stream>>>(hws, dinv, csr, row_st, cnt, cb0, cw1, rows2, N);
    gather_final<<<nb_g, 256, 0, stream>>>((const unsigned short*)rows2, dinv, csr, row_st, cnt,
                                           cb1, pw, pb, out, hout, N);
}